// Round 1
// baseline (504.625 us; speedup 1.0000x reference)
//
#include <hip/hip_runtime.h>

#define CC 64
#define HH 512
#define WW 60
#define PP (HH*WW)            // 30720 positions per (b, channel)
#define PT 128                // positions per block
#define SW 256                // staged floats per ci row ([p0-60, p0+196))
#define NBLK (PP/PT)          // 240
#define NB 16                 // batch

// wt2[(ci*3+kh)*64 + co] = w[co][ci][kh][1]  (only middle kw column matters)
__global__ void transpose_w(const float* __restrict__ w, float* __restrict__ wt2){
    int idx = blockIdx.x * 256 + threadIdx.x;
    if (idx < CC * CC * 3){
        int co = idx & 63;
        int r  = idx >> 6;            // ci*3 + kh
        int ci = r / 3, kh = r - ci * 3;
        wt2[idx] = w[((co * CC + ci) * 3 + kh) * 3 + 1];
    }
}

// PASS 1: out = relu(conv(x) at p) + (w<59 ? x[p+1] : 0)          (down)
// PASS 2: out = down[p] + (w<59 ? relu(conv(down) at p+1) : 0)    (final)
template<int PASS>
__global__ __launch_bounds__(256, 2) void pass_kernel(
    const float* __restrict__ in, const float* __restrict__ wt2,
    const float* __restrict__ bias, float* __restrict__ outp)
{
    __shared__ float xs[CC][SW];          // 64 KB
    const int tid  = threadIdx.x;
    const int lane = tid & 63;
    const int wv   = __builtin_amdgcn_readfirstlane(tid >> 6);   // wave id, SGPR
    const int b    = blockIdx.y;
    const int p0   = blockIdx.x * PT;
    const int base = p0 - 60;             // staged range start (may be <0 / >PP-SW)
    const float* inb = in + (size_t)b * CC * PP;

    // ---- stage: each wave loads 16 ci rows, 64 lanes x float4 = 256 floats/row
    for (int r = 0; r < 16; ++r){
        int ci = wv * 16 + r;
        int cp = base + lane * 4;         // base%4==0, PP%4==0 -> chunks never straddle
        float4 v = make_float4(0.f, 0.f, 0.f, 0.f);
        if (cp >= 0 && cp + 4 <= PP)
            v = *(const float4*)(inb + (size_t)ci * PP + cp);
        *(float4*)&xs[ci][lane * 4] = v;  // zero-fill = conv zero padding at h edges
    }
    __syncthreads();

    // ---- compute: wave owns co = wv*16 .. wv*16+15 ; thread owns 2 positions
    float acc[16][2];
    #pragma unroll
    for (int cc = 0; cc < 16; ++cc){ acc[cc][0] = 0.f; acc[cc][1] = 0.f; }
    const int cobase = wv * 16;
    const int xoff = (PASS == 1) ? lane : (lane + 1);   // pass2 convs at q = p+1

    #pragma unroll 2
    for (int ci = 0; ci < CC; ++ci){
        #pragma unroll
        for (int kh = 0; kh < 3; ++kh){
            float xv0 = xs[ci][kh * 60 + xoff];
            float xv1 = xs[ci][kh * 60 + 64 + xoff];
            const float* wrow = wt2 + (ci * 3 + kh) * CC + cobase;  // uniform -> s_load
            #pragma unroll
            for (int cc = 0; cc < 16; ++cc){
                float wvv = wrow[cc];
                acc[cc][0] = __builtin_fmaf(wvv, xv0, acc[cc][0]);
                acc[cc][1] = __builtin_fmaf(wvv, xv1, acc[cc][1]);
            }
        }
    }

    // ---- epilogue
    float bs[16];
    #pragma unroll
    for (int cc = 0; cc < 16; ++cc) bs[cc] = bias[cobase + cc];
    float* outb = outp + (size_t)b * CC * PP;
    #pragma unroll
    for (int pp = 0; pp < 2; ++pp){
        int pl = pp * 64 + lane;          // p - p0
        int p  = p0 + pl;
        unsigned wq = (unsigned)p % 60u;
        bool inner = (wq < 59u);
        #pragma unroll
        for (int cc = 0; cc < 16; ++cc){
            float conv = acc[cc][pp] + bs[cc];
            conv = conv > 0.f ? conv : 0.f;
            float res;
            if (PASS == 1){
                float sh = inner ? xs[cobase + cc][pl + 61] : 0.f;  // x[p+1]
                res = conv + sh;
            } else {
                float dn = xs[cobase + cc][pl + 60];                // down[p]
                res = dn + (inner ? conv : 0.f);
            }
            outb[(size_t)(cobase + cc) * PP + p] = res;
        }
    }
}

extern "C" void kernel_launch(void* const* d_in, const int* in_sizes, int n_in,
                              void* d_out, int out_size, void* d_ws, size_t ws_size,
                              hipStream_t stream){
    const float* x    = (const float*)d_in[0];
    const float* w    = (const float*)d_in[1];
    const float* bias = (const float*)d_in[2];
    float* out  = (float*)d_out;
    float* down = (float*)d_ws;                         // 16*64*30720 floats
    float* wt2  = down + (size_t)NB * CC * PP;          // 12288 floats

    hipLaunchKernelGGL(transpose_w, dim3(48), dim3(256), 0, stream, w, wt2);
    dim3 grid(NBLK, NB);
    hipLaunchKernelGGL((pass_kernel<1>), grid, dim3(256), 0, stream, x,    wt2, bias, down);
    hipLaunchKernelGGL((pass_kernel<2>), grid, dim3(256), 0, stream, down, wt2, bias, out);
}